// Round 11
// baseline (1436.678 us; speedup 1.0000x reference)
//
#include <hip/hip_runtime.h>
#include <math.h>

#define BATCH 8
#define LSEQ 512
#define LAGENT 256
#define DMODEL 512
#define DINNER 1024
#define DSTATE 16
#define DTRANK 32
#define NHEAD 4
#define DHEAD 128
#define NLANES 6

typedef __attribute__((ext_vector_type(8))) short bf16x8;
typedef __attribute__((ext_vector_type(4))) float f32x4;

// Exact 3-way bf16 split: x = h + m + l + O(2^-24 |x|); all subtractions exact.
__device__ __forceinline__ void split3(float x, short& h, short& m, short& l)
{
    unsigned hb = __float_as_uint(x) & 0xFFFF0000u;
    h = (short)(hb >> 16);
    float r1 = x - __uint_as_float(hb);
    unsigned mb = __float_as_uint(r1) & 0xFFFF0000u;
    m = (short)(mb >> 16);
    float r2 = r1 - __uint_as_float(mb);
    l = (short)(__float_as_uint(r2) >> 16);
}

// ---- JIT weight presplit: W[K][N] fp32 -> 3 bf16 planes, fragment-linear ----
__global__ __launch_bounds__(256)
void wsplit_k(const float* __restrict__ W, short* __restrict__ Wp, int K, int N)
{
    int gid = blockIdx.x * 256 + threadIdx.x;
    int lane = gid & 63;
    int rest = gid >> 6;
    int nsl = N >> 4;
    int ns = rest % nsl, kc = rest / nsl;
    int lrow = lane & 15, quad = lane >> 4;
    const float* src = W + (size_t)(kc * 32 + quad * 8) * N + ns * 16 + lrow;
    bf16x8 h, m, l;
#pragma unroll
    for (int j = 0; j < 8; ++j) {
        short hh, mm, ll;
        split3(src[(size_t)j * N], hh, mm, ll);
        h[j] = hh; m[j] = mm; l[j] = ll;
    }
    size_t planeS = (size_t)K * N;
    size_t base = ((size_t)(kc * nsl + ns)) * 512 + lane * 8;
    *(bf16x8*)&Wp[base] = h;
    *(bf16x8*)&Wp[planeS + base] = m;
    *(bf16x8*)&Wp[2 * planeS + base] = l;
}

// fused presplit for the 5 MHA 512x512 weights (one launch)
__global__ __launch_bounds__(256)
void wsplit5_k(const float* __restrict__ W0, const float* __restrict__ W1,
               const float* __restrict__ W2, const float* __restrict__ W3,
               const float* __restrict__ W4, short* __restrict__ Wp)
{
    const float* Ws[5] = {W0, W1, W2, W3, W4};
    const float* W = Ws[blockIdx.y];
    short* dst = Wp + (size_t)blockIdx.y * 786432;
    const int K = 512, N = 512;
    int gid = blockIdx.x * 256 + threadIdx.x;
    int lane = gid & 63;
    int rest = gid >> 6;
    int nsl = N >> 4;
    int ns = rest % nsl, kc = rest / nsl;
    int lrow = lane & 15, quad = lane >> 4;
    const float* src = W + (size_t)(kc * 32 + quad * 8) * N + ns * 16 + lrow;
    bf16x8 h, m, l;
#pragma unroll
    for (int j = 0; j < 8; ++j) {
        short hh, mm, ll;
        split3(src[(size_t)j * N], hh, mm, ll);
        h[j] = hh; m[j] = mm; l[j] = ll;
    }
    size_t planeS = (size_t)K * N;
    size_t base = ((size_t)(kc * nsl + ns)) * 512 + lane * 8;
    *(bf16x8*)&dst[base] = h;
    *(bf16x8*)&dst[planeS + base] = m;
    *(bf16x8*)&dst[2 * planeS + base] = l;
}

// ---- gemm6f: A = 3 pre-split bf16 planes (row-linear), B = pre-split fragment-linear ----
template<int BM, int BN, int WM, int WN>
__global__ __launch_bounds__(256)
void gemm6f(const unsigned short* __restrict__ Ap0,
            const unsigned short* __restrict__ Ap1,
            const unsigned short* __restrict__ Ap2, int lda,
            const short* __restrict__ Wp,
            const float* __restrict__ bias,
            float* __restrict__ C, int ldc,
            int M, int N, int K, int act, int addC)
{
    constexpr int MT = BM / WM / 16;
    constexpr int NT = BN / WN / 16;
    constexpr int ASL = BM / 16;
    constexpr int BSL = BN / 16;
    constexpr int BITER = (3 * BSL) / 4;
    constexpr int PSH = (BSL == 8) ? 9 : 8;
    __shared__ short Asl[3][ASL * 520];
    __shared__ short Bsl[3][BSL * 512];

    const int tid = threadIdx.x;
    const int w = tid >> 6, lane = tid & 63;
    const int lrow = lane & 15, quad = lane >> 4;
    const int aslab0 = (w % WM) * MT;
    const int bslab0 = (w / WM) * NT;
    const int m0 = blockIdx.y * BM, n0 = blockIdx.x * BN;
    const size_t planeS = (size_t)K * N;

    f32x4 acc[MT][NT] = {};

    for (int k0 = 0; k0 < K; k0 += 32) {
        __syncthreads();
#pragma unroll
        for (int i = 0; i < BM / 32; ++i) {
            int v = tid + 256 * i;
            int row = v >> 3;
            int kq = (v & 7) * 4;
            size_t g = (size_t)(m0 + row) * lda + k0 + kq;
            int off = (row >> 4) * 520 + (((kq >> 3) << 4) + (row & 15)) * 8 + (kq & 7);
            *(short4*)&Asl[0][off] = *(const short4*)&Ap0[g];
            *(short4*)&Asl[1][off] = *(const short4*)&Ap1[g];
            *(short4*)&Asl[2][off] = *(const short4*)&Ap2[g];
        }
        {
            const short* wb = Wp + ((size_t)(k0 >> 5) * (N >> 4) + (n0 >> 4)) * 512;
#pragma unroll
            for (int i = 0; i < BITER; ++i) {
                int idx = tid + 256 * i;
                int p = idx >> PSH;
                int r = idx & ((1 << PSH) - 1);
                *(int4*)&Bsl[p][r * 8] = *(const int4*)(wb + p * planeS + r * 8);
            }
        }
        __syncthreads();

        bf16x8 af[3][MT];
#pragma unroll
        for (int p = 0; p < 3; ++p)
#pragma unroll
            for (int i = 0; i < MT; ++i)
                af[p][i] = *(const bf16x8*)&Asl[p][(aslab0 + i) * 520 + lane * 8];

#pragma unroll
        for (int pb = 0; pb < 3; ++pb) {
            bf16x8 bfr[NT];
#pragma unroll
            for (int j = 0; j < NT; ++j)
                bfr[j] = *(const bf16x8*)&Bsl[pb][(bslab0 + j) * 512 + lane * 8];
            const int npa = (pb == 0) ? 3 : (pb == 1 ? 2 : 1);
#pragma unroll
            for (int pa = 0; pa < 3; ++pa) {
                if (pa >= npa) break;
#pragma unroll
                for (int i = 0; i < MT; ++i)
#pragma unroll
                    for (int j = 0; j < NT; ++j)
                        acc[i][j] = __builtin_amdgcn_mfma_f32_16x16x32_bf16(
                            af[pa][i], bfr[j], acc[i][j], 0, 0, 0);
            }
        }
    }

#pragma unroll
    for (int i = 0; i < MT; ++i) {
        int mbase = m0 + (aslab0 + i) * 16 + quad * 4;
#pragma unroll
        for (int j = 0; j < NT; ++j) {
            int n = n0 + (bslab0 + j) * 16 + lrow;
            float bv = bias ? bias[n] : 0.f;
#pragma unroll
            for (int r = 0; r < 4; ++r) {
                size_t off = (size_t)(mbase + r) * ldc + n;
                float v = acc[i][j][r] + bv;
                if (act == 1) v = (v > 20.f) ? v : log1pf(__expf(v));
                if (addC) v += C[off];
                C[off] = v;
            }
        }
    }
}

// ---- gemm6g: A fp32 (in-kernel split), B pre-split fragment-linear ----
template<int BM, int BN, int WM, int WN>
__global__ __launch_bounds__(256)
void gemm6g(const float* __restrict__ A, int lda,
            const short* __restrict__ Wp,
            const float* __restrict__ bias,
            float* __restrict__ C, int ldc,
            int M, int N, int K, int act, int addC)
{
    constexpr int MT = BM / WM / 16;
    constexpr int NT = BN / WN / 16;
    constexpr int ASL = BM / 16;
    constexpr int BSL = BN / 16;
    constexpr int BITER = (3 * BSL) / 4;
    constexpr int PSH = (BSL == 8) ? 9 : 8;
    __shared__ short Asl[3][ASL * 520];
    __shared__ short Bsl[3][BSL * 512];

    const int tid = threadIdx.x;
    const int w = tid >> 6, lane = tid & 63;
    const int lrow = lane & 15, quad = lane >> 4;
    const int aslab0 = (w % WM) * MT;
    const int bslab0 = (w / WM) * NT;
    const int m0 = blockIdx.y * BM, n0 = blockIdx.x * BN;
    const size_t planeS = (size_t)K * N;

    f32x4 acc[MT][NT] = {};

    for (int k0 = 0; k0 < K; k0 += 32) {
        __syncthreads();
#pragma unroll
        for (int i = 0; i < BM / 32; ++i) {
            int v = tid + 256 * i;
            int row = v >> 3;
            int kq = (v & 7) * 4;
            float4 val = *(const float4*)&A[(size_t)(m0 + row) * lda + k0 + kq];
            int off = (row >> 4) * 520 + (((kq >> 3) << 4) + (row & 15)) * 8 + (kq & 7);
            short h[4], mm_[4], l[4];
            split3(val.x, h[0], mm_[0], l[0]);
            split3(val.y, h[1], mm_[1], l[1]);
            split3(val.z, h[2], mm_[2], l[2]);
            split3(val.w, h[3], mm_[3], l[3]);
            *(short4*)&Asl[0][off] = make_short4(h[0], h[1], h[2], h[3]);
            *(short4*)&Asl[1][off] = make_short4(mm_[0], mm_[1], mm_[2], mm_[3]);
            *(short4*)&Asl[2][off] = make_short4(l[0], l[1], l[2], l[3]);
        }
        {
            const short* wb = Wp + ((size_t)(k0 >> 5) * (N >> 4) + (n0 >> 4)) * 512;
#pragma unroll
            for (int i = 0; i < BITER; ++i) {
                int idx = tid + 256 * i;
                int p = idx >> PSH;
                int r = idx & ((1 << PSH) - 1);
                *(int4*)&Bsl[p][r * 8] = *(const int4*)(wb + p * planeS + r * 8);
            }
        }
        __syncthreads();

        bf16x8 af[3][MT];
#pragma unroll
        for (int p = 0; p < 3; ++p)
#pragma unroll
            for (int i = 0; i < MT; ++i)
                af[p][i] = *(const bf16x8*)&Asl[p][(aslab0 + i) * 520 + lane * 8];

#pragma unroll
        for (int pb = 0; pb < 3; ++pb) {
            bf16x8 bfr[NT];
#pragma unroll
            for (int j = 0; j < NT; ++j)
                bfr[j] = *(const bf16x8*)&Bsl[pb][(bslab0 + j) * 512 + lane * 8];
            const int npa = (pb == 0) ? 3 : (pb == 1 ? 2 : 1);
#pragma unroll
            for (int pa = 0; pa < 3; ++pa) {
                if (pa >= npa) break;
#pragma unroll
                for (int i = 0; i < MT; ++i)
#pragma unroll
                    for (int j = 0; j < NT; ++j)
                        acc[i][j] = __builtin_amdgcn_mfma_f32_16x16x32_bf16(
                            af[pa][i], bfr[j], acc[i][j], 0, 0, 0);
            }
        }
    }

#pragma unroll
    for (int i = 0; i < MT; ++i) {
        int mbase = m0 + (aslab0 + i) * 16 + quad * 4;
#pragma unroll
        for (int j = 0; j < NT; ++j) {
            int n = n0 + (bslab0 + j) * 16 + lrow;
            float bv = bias ? bias[n] : 0.f;
#pragma unroll
            for (int r = 0; r < 4; ++r) {
                size_t off = (size_t)(mbase + r) * ldc + n;
                float v = acc[i][j][r] + bv;
                if (act == 1) v = (v > 20.f) ? v : log1pf(__expf(v));
                if (addC) v += C[off];
                C[off] = v;
            }
        }
    }
}

// ---- split-K variant for x_proj: 64x64 tile, K-chunk per blockIdx.z, partials out ----
__global__ __launch_bounds__(256)
void gemm6sk(const float* __restrict__ A, int lda,
             const float* __restrict__ W, int N,
             float* __restrict__ P, int M, int KC)
{
    constexpr int BM = 64, BN = 64, WM = 2, WN = 2;
    constexpr int MT = BM / WM / 16, NT = BN / WN / 16;
    __shared__ short Asl[3][4 * 520];
    __shared__ short Bsl[3][4 * 520];

    const int tid = threadIdx.x;
    const int w = tid >> 6, lane = tid & 63;
    const int lrow = lane & 15, quad = lane >> 4;
    const int aslab0 = (w % WM) * MT;
    const int bslab0 = (w / WM) * NT;
    const int m0 = blockIdx.y * BM, n0 = blockIdx.x * BN;
    const int kbeg = blockIdx.z * KC;

    f32x4 acc[MT][NT] = {};

    for (int k0 = kbeg; k0 < kbeg + KC; k0 += 32) {
        __syncthreads();
#pragma unroll
        for (int i = 0; i < BM / 32; ++i) {
            int v = tid + 256 * i;
            int row = v >> 3;
            int kq = (v & 7) * 4;
            float4 val = *(const float4*)&A[(size_t)(m0 + row) * lda + k0 + kq];
            int off = (row >> 4) * 520 + (((kq >> 3) << 4) + (row & 15)) * 8 + (kq & 7);
            short h[4], mm_[4], l[4];
            split3(val.x, h[0], mm_[0], l[0]);
            split3(val.y, h[1], mm_[1], l[1]);
            split3(val.z, h[2], mm_[2], l[2]);
            split3(val.w, h[3], mm_[3], l[3]);
            *(short4*)&Asl[0][off] = make_short4(h[0], h[1], h[2], h[3]);
            *(short4*)&Asl[1][off] = make_short4(mm_[0], mm_[1], mm_[2], mm_[3]);
            *(short4*)&Asl[2][off] = make_short4(l[0], l[1], l[2], l[3]);
        }
        {
            int v = tid;
            int kp = v >> 4;
            int nc = (v & 15) * 4;
            int k1 = kp * 2;
            float4 r0 = *(const float4*)&W[(size_t)(k0 + k1) * N + n0 + nc];
            float4 r1 = *(const float4*)&W[(size_t)(k0 + k1 + 1) * N + n0 + nc];
            const float e0[4] = {r0.x, r0.y, r0.z, r0.w};
            const float e1[4] = {r1.x, r1.y, r1.z, r1.w};
#pragma unroll
            for (int e = 0; e < 4; ++e) {
                int n = nc + e;
                int off = (n >> 4) * 520 + (((k1 >> 3) << 4) + (n & 15)) * 8 + (k1 & 7);
                short h0, m0_, l0, h1, m1_, l1;
                split3(e0[e], h0, m0_, l0);
                split3(e1[e], h1, m1_, l1);
                *(short2*)&Bsl[0][off] = make_short2(h0, h1);
                *(short2*)&Bsl[1][off] = make_short2(m0_, m1_);
                *(short2*)&Bsl[2][off] = make_short2(l0, l1);
            }
        }
        __syncthreads();

        bf16x8 af[3][MT];
#pragma unroll
        for (int p = 0; p < 3; ++p)
#pragma unroll
            for (int i = 0; i < MT; ++i)
                af[p][i] = *(const bf16x8*)&Asl[p][(aslab0 + i) * 520 + lane * 8];

#pragma unroll
        for (int pb = 0; pb < 3; ++pb) {
            bf16x8 bfr[NT];
#pragma unroll
            for (int j = 0; j < NT; ++j)
                bfr[j] = *(const bf16x8*)&Bsl[pb][(bslab0 + j) * 520 + lane * 8];
            const int npa = (pb == 0) ? 3 : (pb == 1 ? 2 : 1);
#pragma unroll
            for (int pa = 0; pa < 3; ++pa) {
                if (pa >= npa) break;
#pragma unroll
                for (int i = 0; i < MT; ++i)
#pragma unroll
                    for (int j = 0; j < NT; ++j)
                        acc[i][j] = __builtin_amdgcn_mfma_f32_16x16x32_bf16(
                            af[pa][i], bfr[j], acc[i][j], 0, 0, 0);
            }
        }
    }

    float* Pz = P + (size_t)blockIdx.z * M * 64;
#pragma unroll
    for (int i = 0; i < MT; ++i) {
        int mbase = m0 + (aslab0 + i) * 16 + quad * 4;
#pragma unroll
        for (int j = 0; j < NT; ++j) {
            int n = n0 + (bslab0 + j) * 16 + lrow;
#pragma unroll
            for (int r = 0; r < 4; ++r)
                Pz[(size_t)(mbase + r) * 64 + n] = acc[i][j][r];
        }
    }
}

// reduce 8 K-chunk partials -> DBL (float4 over 4096x64)
__global__ __launch_bounds__(256)
void xred_k(const float* __restrict__ P, float* __restrict__ D)
{
    int i = blockIdx.x * 256 + threadIdx.x;
    const float4* p = (const float4*)P;
    float4 a = p[i];
#pragma unroll
    for (int z = 1; z < 8; ++z) {
        float4 b = p[(size_t)z * 65536 + i];
        a.x += b.x; a.y += b.y; a.z += b.z; a.w += b.w;
    }
    ((float4*)D)[i] = a;
}

// ---------------- RMSNorm -> 3 pre-split bf16 planes ----------------
__global__ __launch_bounds__(256)
void rmsnorm3_k(const float* __restrict__ X, const float* __restrict__ w,
                unsigned short* __restrict__ P0, unsigned short* __restrict__ P1,
                unsigned short* __restrict__ P2)
{
    int wid = threadIdx.x >> 6, lane = threadIdx.x & 63;
    int row = blockIdx.x * 4 + wid;
    const float* xr = X + (size_t)row * DMODEL;
    float v[8];
    float ss = 0.f;
#pragma unroll
    for (int j = 0; j < 8; ++j) { v[j] = xr[lane + 64 * j]; ss = fmaf(v[j], v[j], ss); }
#pragma unroll
    for (int off = 32; off >= 1; off >>= 1) ss += __shfl_xor(ss, off);
    float scale = rsqrtf(ss * (1.f / 512.f) + 1e-5f);
#pragma unroll
    for (int j = 0; j < 8; ++j) {
        int col = lane + 64 * j;
        float val = v[j] * scale * w[col];
        short hh, mm, ll;
        split3(val, hh, mm, ll);
        size_t o = (size_t)row * DMODEL + col;
        P0[o] = (unsigned short)hh;
        P1[o] = (unsigned short)mm;
        P2[o] = (unsigned short)ll;
    }
}

// ---------------- causal depthwise conv (K=4) + SiLU, float4 over d ----------------
__global__ __launch_bounds__(256)
void conv_silu_k(const float* __restrict__ XZ, const float* __restrict__ cw,
                 const float* __restrict__ cb, float* __restrict__ XC)
{
    int idx = blockIdx.x * 256 + threadIdx.x;
    int d4 = (idx & 255) * 4;
    int t = (idx >> 8) & 511;
    int b = idx >> 17;
    float4 wv[4];
#pragma unroll
    for (int e = 0; e < 4; ++e) wv[e] = *(const float4*)&cw[(d4 + e) * 4];
    float4 bv = *(const float4*)&cb[d4];
    float s[4] = {bv.x, bv.y, bv.z, bv.w};
#pragma unroll
    for (int k = 0; k < 4; ++k) {
        int tt = t + k - 3;
        if (tt >= 0) {
            float4 x = *(const float4*)&XZ[((size_t)(b * 512 + tt)) * 2048 + d4];
            const float xe[4] = {x.x, x.y, x.z, x.w};
            const float we[4] = {wv[0][k], wv[1][k], wv[2][k], wv[3][k]};
#pragma unroll
            for (int e = 0; e < 4; ++e) s[e] = fmaf(we[e], xe[e], s[e]);
        }
    }
    float4 o;
    o.x = s[0] / (1.f + __expf(-s[0]));
    o.y = s[1] / (1.f + __expf(-s[1]));
    o.z = s[2] / (1.f + __expf(-s[2]));
    o.w = s[3] / (1.f + __expf(-s[3]));
    *(float4*)&XC[((size_t)(b * 512 + t)) * 1024 + d4] = o;
}

// ---------------- chunked selective scan ----------------
// Phase 1: local scan -> local y into XZ xc-half (stride 2048), SC, DS.
__global__ __launch_bounds__(128)
void scan1_k(const float* __restrict__ DELTA, const float* __restrict__ XC,
             const float* __restrict__ DBL, const float* __restrict__ A_log,
             const float* __restrict__ Dsk, float* __restrict__ YL,
             float* __restrict__ SC, float* __restrict__ DS)
{
    __shared__ float BC[64][32];
    const int tid = threadIdx.x;
    const int d = blockIdx.x * 128 + tid;
    const int chunk = blockIdx.y;
    const int b = blockIdx.z;
    const int t0 = chunk * 64;

#pragma unroll
    for (int i = 0; i < 16; ++i) {
        int idx = tid + 128 * i;
        int t = idx >> 5, j = idx & 31;
        BC[t][j] = DBL[(size_t)(b * 512 + t0 + t) * 64 + 32 + j];
    }
    float Ac[16];
#pragma unroll
    for (int n = 0; n < 16; ++n) Ac[n] = -__expf(A_log[d * 16 + n]);
    float Dv = Dsk[d];
    __syncthreads();

    const float* dp = DELTA + ((size_t)(b * 512 + t0)) * 1024 + d;
    const float* up = XC    + ((size_t)(b * 512 + t0)) * 1024 + d;
    float* yp       = YL    + ((size_t)(b * 512 + t0)) * 2048 + d;

    float h[16];
#pragma unroll
    for (int n = 0; n < 16; ++n) h[n] = 0.f;
    float dsum = 0.f;

    for (int tb = 0; tb < 64; tb += 4) {
        float dl[4], ul[4];
#pragma unroll
        for (int j = 0; j < 4; ++j) {
            dl[j] = dp[(tb + j) * 1024];
            ul[j] = up[(tb + j) * 1024];
        }
#pragma unroll
        for (int j = 0; j < 4; ++j) {
            int t = tb + j;
            float delta = dl[j], u = ul[j];
            dsum += delta;
            float du = delta * u;
            float y = 0.f;
#pragma unroll
            for (int n = 0; n < 16; ++n) {
                h[n] = fmaf(__expf(delta * Ac[n]), h[n], du * BC[t][n]);
                y = fmaf(h[n], BC[t][16 + n], y);
            }
            yp[t * 2048] = fmaf(u, Dv, y);
        }
    }

    float* sc = SC + ((size_t)((b * 8 + chunk) * 1024 + d)) * 16;
#pragma unroll
    for (int n = 0; n < 16; ++n) sc[n] = h[n];
    DS[(size_t)(b * 8 + chunk) * 1024 + d] = dsum;
}

__global__ __launch_bounds__(256)
void scan2_k(const float* __restrict__ A_log, float* __restrict__ SC,
             const float* __restrict__ DS)
{
    int gid = blockIdx.x * 256 + threadIdx.x;
    int n = gid & 15;
    int d = (gid >> 4) & 1023;
    int b = gid >> 14;
    float Ac = -__expf(A_log[d * 16 + n]);
    float carry = 0.f;
#pragma unroll
    for (int c = 0; c < 8; ++c) {
        size_t off = ((size_t)((b * 8 + c) * 1024 + d)) * 16 + n;
        float s = SC[off];
        SC[off] = carry;
        carry = fmaf(__expf(Ac * DS[(size_t)(b * 8 + c) * 1024 + d]), carry, s);
    }
}

// Phase 3: y = (ylocal + h0-correction) * silu(z) -> 3 bf16 planes (for out_proj gemm6f)
__global__ __launch_bounds__(128)
void scan3_k(const float* __restrict__ DELTA, const float* __restrict__ DBL,
             const float* __restrict__ A_log, const float* __restrict__ H0,
             const float* __restrict__ XZ, unsigned short* __restrict__ Yp0,
             unsigned short* __restrict__ Yp1, unsigned short* __restrict__ Yp2)
{
    __shared__ float Cs[64][16];
    const int tid = threadIdx.x;
    const int d = blockIdx.x * 128 + tid;
    const int chunk = blockIdx.y;
    const int b = blockIdx.z;
    const int t0 = chunk * 64;

#pragma unroll
    for (int i = 0; i < 8; ++i) {
        int idx = tid + 128 * i;
        int t = idx >> 4, j = idx & 15;
        Cs[t][j] = DBL[(size_t)(b * 512 + t0 + t) * 64 + 48 + j];
    }
    float Ac[16], h0[16];
#pragma unroll
    for (int n = 0; n < 16; ++n) Ac[n] = -__expf(A_log[d * 16 + n]);
    const float* h0p = H0 + ((size_t)((b * 8 + chunk) * 1024 + d)) * 16;
#pragma unroll
    for (int n = 0; n < 16; ++n) h0[n] = h0p[n];
    __syncthreads();

    const float* dp = DELTA + ((size_t)(b * 512 + t0)) * 1024 + d;
    const float* yl = XZ    + ((size_t)(b * 512 + t0)) * 2048 + d;          // xc half
    const float* zp = XZ    + ((size_t)(b * 512 + t0)) * 2048 + 1024 + d;   // z half
    size_t obase = (size_t)(b * 512 + t0) * 1024 + d;

    float cum = 0.f;
    for (int tb = 0; tb < 64; tb += 4) {
        float dl[4], yv[4], zl[4];
#pragma unroll
        for (int j = 0; j < 4; ++j) {
            dl[j] = dp[(tb + j) * 1024];
            yv[j] = yl[(tb + j) * 2048];
            zl[j] = zp[(tb + j) * 2048];
        }
#pragma unroll
        for (int j = 0; j < 4; ++j) {
            int t = tb + j;
            float p = 0.f;
            if (chunk != 0) {
                cum += dl[j];
#pragma unroll
                for (int n = 0; n < 16; ++n)
                    p = fmaf(h0[n] * __expf(Ac[n] * cum), Cs[t][n], p);
            }
            float z = zl[j];
            float g = (yv[j] + p) * (z / (1.f + __expf(-z)));
            short hh, mm, ll;
            split3(g, hh, mm, ll);
            size_t o = obase + (size_t)t * 1024;
            Yp0[o] = (unsigned short)hh;
            Yp1[o] = (unsigned short)mm;
            Yp2[o] = (unsigned short)ll;
        }
    }
}

// ---------------- MFMA flash attention, exact fp32 via bf16x6 ----------------
__global__ __launch_bounds__(256, 1)
void attn_mfma(const float* __restrict__ Qm, const float* __restrict__ Km,
               const float* __restrict__ Vm, float* __restrict__ CTX)
{
    __shared__ short KVs[3][16 * 520];
    __shared__ float Ps[4][16 * 260];
    const int tid = threadIdx.x;
    const int w = tid >> 6, lane = tid & 63;
    const int lrow = lane & 15, quad = lane >> 4;
    const int b = blockIdx.z, h = blockIdx.y;
    const int qw = blockIdx.x * 64 + w * 16;

    bf16x8 qf[3][4];
    {
        const float* qp = Qm + ((size_t)(b * 512 + qw + lrow)) * 512 + h * 128 + quad * 8;
#pragma unroll
        for (int kb = 0; kb < 4; ++kb) {
            float4 v0 = *(const float4*)(qp + kb * 32);
            float4 v1 = *(const float4*)(qp + kb * 32 + 4);
            const float e[8] = {v0.x, v0.y, v0.z, v0.w, v1.x, v1.y, v1.z, v1.w};
#pragma unroll
            for (int j = 0; j < 8; ++j) {
                short hh, mm, ll;
                split3(e[j], hh, mm, ll);
                qf[0][kb][j] = hh; qf[1][kb][j] = mm; qf[2][kb][j] = ll;
            }
        }
    }

    const int sdd = (tid & 31) * 4;
    const int skvb = tid >> 5;
    f32x4 sa[4][4] = {};

    float4 kpre[8];
#pragma unroll
    for (int i = 0; i < 8; ++i)
        kpre[i] = *(const float4*)&Km[((size_t)(b * 256 + skvb + 8 * i)) * 512 + h * 128 + sdd];

    for (int c = 0; c < 4; ++c) {
        if (c) __syncthreads();
        {
            const int kb = sdd >> 5, qd = (sdd >> 3) & 3, jd = sdd & 7;
#pragma unroll
            for (int i = 0; i < 8; ++i) {
                int kv = skvb + 8 * i;
                int off = ((kv >> 4) * 4 + kb) * 520 + ((kv & 15) + 16 * qd) * 8 + jd;
                short h0,m0,l0,h1,m1,l1,h2,m2,l2,h3,m3,l3;
                split3(kpre[i].x,h0,m0,l0); split3(kpre[i].y,h1,m1,l1);
                split3(kpre[i].z,h2,m2,l2); split3(kpre[i].w,h3,m3,l3);
                *(short4*)&KVs[0][off] = make_short4(h0,h1,h2,h3);
                *(short4*)&KVs[1][off] = make_short4(m0,m1,m2,m3);
                *(short4*)&KVs[2][off] = make_short4(l0,l1,l2,l3);
            }
        }
        if (c < 3) {
#pragma unroll
            for (int i = 0; i < 8; ++i)
                kpre[i] = *(const float4*)&Km[((size_t)(b * 256 + (c + 1) * 64 + skvb + 8 * i)) * 512 + h * 128 + sdd];
        }
        __syncthreads();
#pragma unroll
        for (int s = 0; s < 4; ++s) {
#pragma unroll
            for (int kb = 0; kb < 4; ++kb) {
                bf16x8 kf[3];
#pragma unroll
                for (int p = 0; p < 3; ++p)
                    kf[p] = *(const bf16x8*)&KVs[p][(s * 4 + kb) * 520 + lane * 8];
                sa[c][s] = __builtin_amdgcn_mfma_f32_16x16x32_bf16(qf[0][kb], kf[0], sa[c][s], 0, 0, 0);
                sa[c][s] = __builtin_amdgcn_mfma_f32_16x16x32_bf16(qf[0][kb], kf[1], sa[c][s], 0, 0, 0);
                sa[c][s] = __builtin_amdgcn_mfma_f32_16x16x32_bf16(qf[1][kb], kf[0], sa[c][s], 0, 0, 0);
                sa[c][s] = __builtin_amdgcn_mfma_f32_16x16x32_bf16(qf[0][kb], kf[2], sa[c][s], 0, 0, 0);
                sa[c][s] = __builtin_amdgcn_mfma_f32_16x16x32_bf16(qf[1][kb], kf[1], sa[c][s], 0, 0, 0);
                sa[c][s] = __builtin_amdgcn_mfma_f32_16x16x32_bf16(qf[2][kb], kf[0], sa[c][s], 0, 0, 0);
            }
        }
    }

    const float scale = 0.08838834764831845f;
    float mx[4] = {-1e30f, -1e30f, -1e30f, -1e30f};
#pragma unroll
    for (int c = 0; c < 4; ++c)
#pragma unroll
        for (int s = 0; s < 4; ++s)
#pragma unroll
            for (int r = 0; r < 4; ++r) {
                sa[c][s][r] *= scale;
                mx[r] = fmaxf(mx[r], sa[c][s][r]);
            }
#pragma unroll
    for (int r = 0; r < 4; ++r) {
        mx[r] = fmaxf(mx[r], __shfl_xor(mx[r], 1));
        mx[r] = fmaxf(mx[r], __shfl_xor(mx[r], 2));
        mx[r] = fmaxf(mx[r], __shfl_xor(mx[r], 4));
        mx[r] = fmaxf(mx[r], __shfl_xor(mx[r], 8));
    }
    float sum[4] = {0.f, 0.f, 0.f, 0.f};
#pragma unroll
    for (int c = 0; c < 4; ++c)
#pragma unroll
        for (int s = 0; s < 4; ++s)
#pragma unroll
            for (int r = 0; r < 4; ++r) {
                float e = __expf(sa[c][s][r] - mx[r]);
                sa[c][s][r] = e;
                sum[r] += e;
            }
#pragma unroll
    for (int r = 0; r < 4; ++r) {
        sum[r] += __shfl_xor(sum[r], 1);
        sum[r] += __shfl_xor(sum[r], 2);
        sum[r] += __shfl_xor(sum[r], 4);
        sum[r] += __shfl_xor(sum[r], 8);
        sum[r] = 1.f / sum[r];
    }
    {
        float* ps = &Ps[w][0];
#pragma unroll
        for (int c = 0; c < 4; ++c)
#pragma unroll
            for (int s = 0; s < 4; ++s)
#pragma unroll
                for (int r = 0; r < 4; ++r)
                    ps[(quad * 4 + r) * 260 + c * 64 + s * 16 + lrow] = sa[c][s][r] * sum[r];
    }

    const int vdd4 = (tid & 31) * 4;
    const int vkvg = tid >> 5;
    f32x4 oa[8] = {};
    float4 vpre[8];
#pragma unroll
    for (int i = 0; i < 2; ++i) {
        int kv0 = (vkvg + 8 * i) * 4;
#pragma unroll
        for (int rr = 0; rr < 4; ++rr)
            vpre[i * 4 + rr] = *(const float4*)&Vm[((size_t)(b * 256 + kv0 + rr)) * 512 + h * 128 + vdd4];
    }

    for (int c = 0; c < 4; ++c) {
        __syncthreads();
        {
#pragma unroll
            for (int i = 0; i < 2; ++i) {
                int kv0 = (vkvg + 8 * i) * 4;
                int kb2 = kv0 >> 5, qk = (kv0 >> 3) & 3, jb = kv0 & 7;
                const float4 r0 = vpre[i * 4 + 0], r1 = vpre[i * 4 + 1];
                const float4 r2 = vpre[i * 4 + 2], r3 = vpre[i * 4 + 3];
                const float ve[4][4] = {{r0.x, r1.x, r2.x, r3.x},
                                        {r0.y, r1.y, r2.y, r3.y},
                                        {r0.z, r1.z, r2.z, r3.z},
                                        {r0.w, r1.w, r2.w, r3.w}};
#pragma unroll
                for (int e = 0; e < 4; ++e) {
                    int dd = vdd4 + e;
                    int off = ((dd >> 4) * 2 + kb2) * 520 + ((dd & 15) + 16 * qk) * 8 + jb;
                    short h0,m0,l0,h1,m1,l1,h2,m2,l2,h3,m3,l3;
                    split3(ve[e][0],h0,m0,l0); split3(ve[e][1],h1,m1,l1);
                    split3(ve[e][2],h2,m2,l2); split3(ve[e][3],h3,m3,l3);
                    *(short4*)&KVs[0][off] = make_short4(h0,h1,h2,h3);
                    *(short4*)&KVs[1][off] = make_short4(m0,m1,m2,m3);
                    *(short4*)&KVs[2][off] = make_short4(l0,l1,l2,l3);
                }
            }
        }
        if (c < 3) {
#pragma unroll
            for (int i = 0; i < 2; ++i) {
                int kv0 = (vkvg + 8 * i) * 4;
#pragma unroll
                for (int rr = 0; rr < 4; ++rr)
                    vpre[i * 4 + rr] = *(const float4*)&Vm[((size_t)(b * 256 + (c + 1) * 64 + kv0 + rr)) * 512 + h * 128 + vdd4];
            }
        }
        __syncthreads();
#pragma unroll
        for (int kb2 = 0; kb2 < 2; ++kb2) {
            const float* pp = &Ps[w][lrow * 260 + c * 64 + kb2 * 32 + quad * 8];
            float4 a0 = *(const float4*)pp;
            float4 a1 = *(const float4*)(pp + 4);
            const float e[8] = {a0.x, a0.y, a0.z, a0.w, a1.x, a1.y, a1.z, a1.w};
            bf16x8 af[3];
#pragma unroll
            for (int j = 0; j < 8; ++j) {
                short hh, mm, ll;
                split3(e[j], hh, mm, ll);
                af[0][j] = hh; af[1][j] = mm; af[2][j] = ll;
            }
#pragma unroll
            for (int s = 0; s < 8; ++s) {
                bf16x8 vf[3];
#pragma unroll
                for (int p = 0; p < 3; ++p)
                    vf[p] = *(const bf16x8*)&KVs[p][(s * 2 + kb2) * 520 + lane * 8];
                oa[s] = __builtin_amdgcn_mfma_f32_16x16x32_bf16(af[0], vf[0], oa[s], 0, 0, 0);
                oa[s] = __builtin_amdgcn_mfma_f32_16x16x32_bf16(af[0], vf[1], oa[s], 0, 0, 0);
                oa[s] = __builtin_amdgcn_mfma_f32_16x16x32_bf16(af[1], vf[0], oa[s], 0, 0, 0);
                oa[s] = __builtin_amdgcn_mfma_f32_16x16x32_bf16(af[0], vf[2], oa[s], 0, 0, 0);
                oa[s] = __builtin_amdgcn_mfma_f32_16x16x32_bf16(af[1], vf[1], oa[s], 0, 0, 0);
                oa[s] = __builtin_amdgcn_mfma_f32_16x16x32_bf16(af[2], vf[0], oa[s], 0, 0, 0);
            }
        }
    }

#pragma unroll
    for (int s = 0; s < 8; ++s)
#pragma unroll
        for (int r = 0; r < 4; ++r)
            CTX[((size_t)(b * 512 + qw + quad * 4 + r)) * 512 + h * 128 + s * 16 + lrow] = oa[s][r];
}

// ---------------- final linear (512->6) + argmax, one wave per row ----------------
__global__ __launch_bounds__(256)
void head_k(const float* __restrict__ T2, const float* __restrict__ Wout,
            const float* __restrict__ bout, float* __restrict__ out)
{
    int wid = threadIdx.x >> 6, lane = threadIdx.x & 63;
    int row = blockIdx.x * 4 + wid;
    float acc[6] = {0.f, 0.f, 0.f, 0.f, 0.f, 0.f};
    const float* tr = T2 + (size_t)row * 512;
#pragma unroll
    for (int j = 0; j < 8; ++j) {
        int k = lane + 64 * j;
        float t = tr[k];
#pragma unroll
        for (int c = 0; c < 6; ++c) acc[c] = fmaf(t, Wout[k * 6 + c], acc[c]);
    }
#pragma unroll
    for (int c = 0; c < 6; ++c) {
#pragma unroll
        for (int off = 32; off >= 1; off >>= 1) acc[c] += __shfl_xor(acc[c], off);
    }
    if (lane == 0) {
        float best = -1e30f;
        int bi = 0;
#pragma unroll
        for (int c = 0; c < 6; ++c) {
            float v = acc[c] + bout[c];
            out[(size_t)row * 6 + c] = v;
            if (v > best) { best = v; bi = c; }
        }
        out[(size_t)4096 * 6 + row] = (float)bi;
    }
}

extern "C" void kernel_launch(void* const* d_in, const int* in_sizes, int n_in,
                              void* d_out, int out_size, void* d_ws, size_t ws_size,
                              hipStream_t stream)
{
    (void)in_sizes; (void)n_in; (void)out_size; (void)ws_size;
    const float* agent      = (const float*)d_in[0];
    const float* lane       = (const float*)d_in[1];
    const float* lane_in_W  = (const float*)d_in[2];
    const float* lane_in_b  = (const float*)d_in[3];
    const float* norm_w     = (const float*)d_in[4];
    const float* in_proj_W  = (const float*)d_in[5];
    const float* conv_w     = (const float*)d_in[6];
    const float* conv_b     = (const float*)d_in[7];
    const float* x_proj_W   = (const float*)d_in[8];
    const float* dt_proj_W  = (const float*)d_in[9];
    const float* dt_proj_b  = (const float*)d_in[10];
    const float* A_log      = (const float*)d_in[11];
    const float* D_skip     = (const float*)d_in[12];
    const float* out_proj_W = (const float*)d_in[13];
    const float* final_norm_w = (const float*)d_in[14];
    const float* Wq = (const float*)d_in[15];
    const float* Wk = (const float*)d_in[16];
    const float* Wv = (const float*)d_in[17];
    const float* Wo = (const float*)d_in[18];
    const float* bq = (const float*)d_in[19];
    const float* bk = (const float*)d_in[20];
    const float* bv = (const float*)d_in[21];
    const float* bo = (const float*)d_in[22];
    const float* lin_in_W  = (const float*)d_in[23];
    const float* lin_in_b  = (const float*)d_in[24];
    const float* lin_out_W = (const float*)d_in[25];
    const float* lin_out_b = (const float*)d_in[26];

    // Workspace: same 97 MB footprint (rounds 1/3-10). All aliases lifetime-audited:
    //  - local y lives in XZ xc-half (dead after conv) at stride 2048
    //  - gated-y planes: Yp0/Yp1 in Y (16MB), Yp2 in XC+4MB (XC fp32 dead after scan1)
    //  - out_proj W planes at XC (written after scan2), dt W planes at H+1.5M
    float* ws = (float*)d_ws;
    float* X     = ws;                      // 2M floats (4096 x 512)
    float* H     = X + (1 << 21);           // 2M
    float* XZ    = H + (1 << 21);           // 8M  (4096 x 2048)
    float* XC    = XZ + (1 << 23);          // 4M  (4096 x 1024)
    float* DELTA = XC + (1 << 22);          // 4M
    float* Y     = DELTA + (1 << 22);       // 4M
    float* DBL   = Y + (1 << 22);           // 256K (4096 x 64)
    unsigned short* Hp0 = (unsigned short*)H;
    unsigned short* Hp1 = (unsigned short*)(H + (1 << 20));
    unsigned short* Hp2 = (unsigned short*)Y;
    float* PART  = Y + (1 << 20);           // x_proj split-K partials (8MB)
    float* SCb   = H;
    float* DSb   = H + (1 << 20);
    short* DTWP  = (short*)(H + 3 * (1 << 19));   // dt W planes (196KB), post-in_proj window
    short* WPL   = (short*)XC;              // JIT weight planes
    unsigned short* Yp0 = (unsigned short*)Y;
    unsigned short* Yp1 = (unsigned short*)(Y + (1 << 21));
    unsigned short* Yp2 = (unsigned short*)(XC + (1 << 20));
    float* Qb  = XZ;                        // MHA phase
    float* Kb  = XZ + (1 << 21);
    float* Vb  = Kb + (1 << 20);
    float* CTX = Vb + (1 << 20);
    float* AO  = CTX + (1 << 21);
    float* T2  = DELTA;

    dim3 blk(256);
    dim3 sblk(128);
    dim3 sgrid(8, 8, 8);

    // x = lane_features @ lane_in_W + b
    wsplit_k<<<32, blk, 0, stream>>>(lane_in_W, WPL, 128, 512);
    gemm6g<128, 64, 2, 2><<<dim3(8, 32), blk, 0, stream>>>(
        lane, 128, WPL, lane_in_b, X, 512, 4096, 512, 128, 0, 0);

    for (int i = 0; i < 4; ++i) {
        rmsnorm3_k<<<1024, blk, 0, stream>>>(X, norm_w + i * 512, Hp0, Hp1, Hp2);
        wsplit_k<<<512, blk, 0, stream>>>(in_proj_W + (size_t)i * 512 * 2048, WPL, 512, 2048);
        gemm6f<128, 128, 2, 2><<<dim3(16, 32), blk, 0, stream>>>(
            Hp0, Hp1, Hp2, 512, WPL, nullptr, XZ, 2048, 4096, 2048, 512, 0, 0);
        conv_silu_k<<<4096, blk, 0, stream>>>(XZ, conv_w + i * 4096, conv_b + i * 1024, XC);
        gemm6sk<<<dim3(1, 64, 8), blk, 0, stream>>>(
            XC, 1024, x_proj_W + (size_t)i * 1024 * 64, 64, PART, 4096, 128);
        xred_k<<<256, blk, 0, stream>>>(PART, DBL);
        // dt_proj with pre-split W
        wsplit_k<<<16, blk, 0, stream>>>(dt_proj_W + (size_t)i * 32 * 1024, DTWP, 32, 1024);
        gemm6g<128, 64, 2, 2><<<dim3(16, 32), blk, 0, stream>>>(
            DBL, 64, DTWP, dt_proj_b + i * 1024, DELTA, 1024, 4096, 1024, 32, 1, 0);
        // scans: local y -> XZ xc-half; phase 3 gates and emits bf16 planes
        scan1_k<<<sgrid, sblk, 0, stream>>>(DELTA, XC, DBL, A_log + (size_t)i * 1024 * 16,
                                            D_skip + i * 1024, XZ, SCb, DSb);
        scan2_k<<<512, blk, 0, stream>>>(A_log + (size_t)i * 1024 * 16, SCb, DSb);
        wsplit_k<<<256, blk, 0, stream>>>(out_proj_W + (size_t)i * 1024 * 512, WPL, 1024, 512);
        scan3_k<<<sgrid, sblk, 0, stream>>>(DELTA, DBL, A_log + (size_t)i * 1024 * 16,
                                            SCb, XZ, Yp0, Yp1, Yp2);
        // x += ygated @ out_proj: both operands pre-split
        gemm6f<64, 64, 2, 2><<<dim3(8, 64), blk, 0, stream>>>(
            Yp0, Yp1, Yp2, 1024, WPL, nullptr, X, 512, 4096, 512, 1024, 0, 1);
    }

    rmsnorm3_k<<<1024, blk, 0, stream>>>(X, final_norm_w, Hp0, Hp1, Hp2);

    // fused MHA weight presplits into XC
    short* WPq = WPL;
    short* WPk = WPL + 786432;
    short* WPv = WPL + 2 * 786432;
    short* WPo = WPL + 3 * 786432;
    short* WPn = WPL + 4 * 786432;
    wsplit5_k<<<dim3(128, 5), blk, 0, stream>>>(Wq, Wk, Wv, Wo, lin_in_W, WPL);

    gemm6f<128, 64, 2, 2><<<dim3(8, 32), blk, 0, stream>>>(
        Hp0, Hp1, Hp2, 512, WPq, bq, Qb, 512, 4096, 512, 512, 0, 0);
    gemm6g<64, 64, 2, 2><<<dim3(8, 32), blk, 0, stream>>>(
        agent, 512, WPk, bk, Kb, 512, 2048, 512, 512, 0, 0);
    gemm6g<64, 64, 2, 2><<<dim3(8, 32), blk, 0, stream>>>(
        agent, 512, WPv, bv, Vb, 512, 2048, 512, 512, 0, 0);
    attn_mfma<<<dim3(8, 4, 8), blk, 0, stream>>>(Qb, Kb, Vb, CTX);
    gemm6g<64, 64, 2, 2><<<dim3(8, 64), blk, 0, stream>>>(
        CTX, 512, WPo, bo, AO, 512, 4096, 512, 512, 0, 0);
    gemm6g<64, 64, 2, 2><<<dim3(8, 64), blk, 0, stream>>>(
        AO, 512, WPn, lin_in_b, T2, 512, 4096, 512, 512, 0, 0);
    head_k<<<1024, blk, 0, stream>>>(T2, lin_out_W, lin_out_b, (float*)d_out);
}

// Round 12
// 1230.029 us; speedup vs baseline: 1.1680x; 1.1680x over previous
//
#include <hip/hip_runtime.h>
#include <math.h>

#define BATCH 8
#define LSEQ 512
#define LAGENT 256
#define DMODEL 512
#define DINNER 1024
#define DSTATE 16
#define DTRANK 32
#define NHEAD 4
#define DHEAD 128
#define NLANES 6

typedef __attribute__((ext_vector_type(8))) short bf16x8;
typedef __attribute__((ext_vector_type(4))) float f32x4;

// Exact 3-way bf16 split: x = h + m + l + O(2^-24 |x|); all subtractions exact.
__device__ __forceinline__ void split3(float x, short& h, short& m, short& l)
{
    unsigned hb = __float_as_uint(x) & 0xFFFF0000u;
    h = (short)(hb >> 16);
    float r1 = x - __uint_as_float(hb);
    unsigned mb = __float_as_uint(r1) & 0xFFFF0000u;
    m = (short)(mb >> 16);
    float r2 = r1 - __uint_as_float(mb);
    l = (short)(__float_as_uint(r2) >> 16);
}

// ---- JIT weight presplit: W[K][N] fp32 -> 3 bf16 planes, fragment-linear ----
__global__ __launch_bounds__(256)
void wsplit_k(const float* __restrict__ W, short* __restrict__ Wp, int K, int N)
{
    int gid = blockIdx.x * 256 + threadIdx.x;
    int lane = gid & 63;
    int rest = gid >> 6;
    int nsl = N >> 4;
    int ns = rest % nsl, kc = rest / nsl;
    int lrow = lane & 15, quad = lane >> 4;
    const float* src = W + (size_t)(kc * 32 + quad * 8) * N + ns * 16 + lrow;
    bf16x8 h, m, l;
#pragma unroll
    for (int j = 0; j < 8; ++j) {
        short hh, mm, ll;
        split3(src[(size_t)j * N], hh, mm, ll);
        h[j] = hh; m[j] = mm; l[j] = ll;
    }
    size_t planeS = (size_t)K * N;
    size_t base = ((size_t)(kc * nsl + ns)) * 512 + lane * 8;
    *(bf16x8*)&Wp[base] = h;
    *(bf16x8*)&Wp[planeS + base] = m;
    *(bf16x8*)&Wp[2 * planeS + base] = l;
}

// fused presplit for the 5 MHA 512x512 weights (one launch)
__global__ __launch_bounds__(256)
void wsplit5_k(const float* __restrict__ W0, const float* __restrict__ W1,
               const float* __restrict__ W2, const float* __restrict__ W3,
               const float* __restrict__ W4, short* __restrict__ Wp)
{
    const float* Ws[5] = {W0, W1, W2, W3, W4};
    const float* W = Ws[blockIdx.y];
    short* dst = Wp + (size_t)blockIdx.y * 786432;
    const int K = 512, N = 512;
    int gid = blockIdx.x * 256 + threadIdx.x;
    int lane = gid & 63;
    int rest = gid >> 6;
    int nsl = N >> 4;
    int ns = rest % nsl, kc = rest / nsl;
    int lrow = lane & 15, quad = lane >> 4;
    const float* src = W + (size_t)(kc * 32 + quad * 8) * N + ns * 16 + lrow;
    bf16x8 h, m, l;
#pragma unroll
    for (int j = 0; j < 8; ++j) {
        short hh, mm, ll;
        split3(src[(size_t)j * N], hh, mm, ll);
        h[j] = hh; m[j] = mm; l[j] = ll;
    }
    size_t planeS = (size_t)K * N;
    size_t base = ((size_t)(kc * nsl + ns)) * 512 + lane * 8;
    *(bf16x8*)&dst[base] = h;
    *(bf16x8*)&dst[planeS + base] = m;
    *(bf16x8*)&dst[2 * planeS + base] = l;
}

// ---- gemm6f: A = 3 pre-split bf16 planes (row-linear), B = pre-split fragment-linear ----
template<int BM, int BN, int WM, int WN>
__global__ __launch_bounds__(256)
void gemm6f(const unsigned short* __restrict__ Ap0,
            const unsigned short* __restrict__ Ap1,
            const unsigned short* __restrict__ Ap2, int lda,
            const short* __restrict__ Wp,
            const float* __restrict__ bias,
            float* __restrict__ C, int ldc,
            int M, int N, int K, int act, int addC)
{
    constexpr int MT = BM / WM / 16;
    constexpr int NT = BN / WN / 16;
    constexpr int ASL = BM / 16;
    constexpr int BSL = BN / 16;
    constexpr int BITER = (3 * BSL) / 4;
    constexpr int PSH = (BSL == 8) ? 9 : 8;
    __shared__ short Asl[3][ASL * 520];
    __shared__ short Bsl[3][BSL * 512];

    const int tid = threadIdx.x;
    const int w = tid >> 6, lane = tid & 63;
    const int lrow = lane & 15, quad = lane >> 4;
    const int aslab0 = (w % WM) * MT;
    const int bslab0 = (w / WM) * NT;
    const int m0 = blockIdx.y * BM, n0 = blockIdx.x * BN;
    const size_t planeS = (size_t)K * N;

    f32x4 acc[MT][NT] = {};

    for (int k0 = 0; k0 < K; k0 += 32) {
        __syncthreads();
#pragma unroll
        for (int i = 0; i < BM / 32; ++i) {
            int v = tid + 256 * i;
            int row = v >> 3;
            int kq = (v & 7) * 4;
            size_t g = (size_t)(m0 + row) * lda + k0 + kq;
            int off = (row >> 4) * 520 + (((kq >> 3) << 4) + (row & 15)) * 8 + (kq & 7);
            *(short4*)&Asl[0][off] = *(const short4*)&Ap0[g];
            *(short4*)&Asl[1][off] = *(const short4*)&Ap1[g];
            *(short4*)&Asl[2][off] = *(const short4*)&Ap2[g];
        }
        {
            const short* wb = Wp + ((size_t)(k0 >> 5) * (N >> 4) + (n0 >> 4)) * 512;
#pragma unroll
            for (int i = 0; i < BITER; ++i) {
                int idx = tid + 256 * i;
                int p = idx >> PSH;
                int r = idx & ((1 << PSH) - 1);
                *(int4*)&Bsl[p][r * 8] = *(const int4*)(wb + p * planeS + r * 8);
            }
        }
        __syncthreads();

        bf16x8 af[3][MT];
#pragma unroll
        for (int p = 0; p < 3; ++p)
#pragma unroll
            for (int i = 0; i < MT; ++i)
                af[p][i] = *(const bf16x8*)&Asl[p][(aslab0 + i) * 520 + lane * 8];

#pragma unroll
        for (int pb = 0; pb < 3; ++pb) {
            bf16x8 bfr[NT];
#pragma unroll
            for (int j = 0; j < NT; ++j)
                bfr[j] = *(const bf16x8*)&Bsl[pb][(bslab0 + j) * 512 + lane * 8];
            const int npa = (pb == 0) ? 3 : (pb == 1 ? 2 : 1);
#pragma unroll
            for (int pa = 0; pa < 3; ++pa) {
                if (pa >= npa) break;
#pragma unroll
                for (int i = 0; i < MT; ++i)
#pragma unroll
                    for (int j = 0; j < NT; ++j)
                        acc[i][j] = __builtin_amdgcn_mfma_f32_16x16x32_bf16(
                            af[pa][i], bfr[j], acc[i][j], 0, 0, 0);
            }
        }
    }

#pragma unroll
    for (int i = 0; i < MT; ++i) {
        int mbase = m0 + (aslab0 + i) * 16 + quad * 4;
#pragma unroll
        for (int j = 0; j < NT; ++j) {
            int n = n0 + (bslab0 + j) * 16 + lrow;
            float bv = bias ? bias[n] : 0.f;
#pragma unroll
            for (int r = 0; r < 4; ++r) {
                size_t off = (size_t)(mbase + r) * ldc + n;
                float v = acc[i][j][r] + bv;
                if (act == 1) v = (v > 20.f) ? v : log1pf(__expf(v));
                if (addC) v += C[off];
                C[off] = v;
            }
        }
    }
}

// ---- gemm6g: A fp32 (in-kernel split), B pre-split fragment-linear ----
template<int BM, int BN, int WM, int WN>
__global__ __launch_bounds__(256)
void gemm6g(const float* __restrict__ A, int lda,
            const short* __restrict__ Wp,
            const float* __restrict__ bias,
            float* __restrict__ C, int ldc,
            int M, int N, int K, int act, int addC)
{
    constexpr int MT = BM / WM / 16;
    constexpr int NT = BN / WN / 16;
    constexpr int ASL = BM / 16;
    constexpr int BSL = BN / 16;
    constexpr int BITER = (3 * BSL) / 4;
    constexpr int PSH = (BSL == 8) ? 9 : 8;
    __shared__ short Asl[3][ASL * 520];
    __shared__ short Bsl[3][BSL * 512];

    const int tid = threadIdx.x;
    const int w = tid >> 6, lane = tid & 63;
    const int lrow = lane & 15, quad = lane >> 4;
    const int aslab0 = (w % WM) * MT;
    const int bslab0 = (w / WM) * NT;
    const int m0 = blockIdx.y * BM, n0 = blockIdx.x * BN;
    const size_t planeS = (size_t)K * N;

    f32x4 acc[MT][NT] = {};

    for (int k0 = 0; k0 < K; k0 += 32) {
        __syncthreads();
#pragma unroll
        for (int i = 0; i < BM / 32; ++i) {
            int v = tid + 256 * i;
            int row = v >> 3;
            int kq = (v & 7) * 4;
            float4 val = *(const float4*)&A[(size_t)(m0 + row) * lda + k0 + kq];
            int off = (row >> 4) * 520 + (((kq >> 3) << 4) + (row & 15)) * 8 + (kq & 7);
            short h[4], mm_[4], l[4];
            split3(val.x, h[0], mm_[0], l[0]);
            split3(val.y, h[1], mm_[1], l[1]);
            split3(val.z, h[2], mm_[2], l[2]);
            split3(val.w, h[3], mm_[3], l[3]);
            *(short4*)&Asl[0][off] = make_short4(h[0], h[1], h[2], h[3]);
            *(short4*)&Asl[1][off] = make_short4(mm_[0], mm_[1], mm_[2], mm_[3]);
            *(short4*)&Asl[2][off] = make_short4(l[0], l[1], l[2], l[3]);
        }
        {
            const short* wb = Wp + ((size_t)(k0 >> 5) * (N >> 4) + (n0 >> 4)) * 512;
#pragma unroll
            for (int i = 0; i < BITER; ++i) {
                int idx = tid + 256 * i;
                int p = idx >> PSH;
                int r = idx & ((1 << PSH) - 1);
                *(int4*)&Bsl[p][r * 8] = *(const int4*)(wb + p * planeS + r * 8);
            }
        }
        __syncthreads();

        bf16x8 af[3][MT];
#pragma unroll
        for (int p = 0; p < 3; ++p)
#pragma unroll
            for (int i = 0; i < MT; ++i)
                af[p][i] = *(const bf16x8*)&Asl[p][(aslab0 + i) * 520 + lane * 8];

#pragma unroll
        for (int pb = 0; pb < 3; ++pb) {
            bf16x8 bfr[NT];
#pragma unroll
            for (int j = 0; j < NT; ++j)
                bfr[j] = *(const bf16x8*)&Bsl[pb][(bslab0 + j) * 512 + lane * 8];
            const int npa = (pb == 0) ? 3 : (pb == 1 ? 2 : 1);
#pragma unroll
            for (int pa = 0; pa < 3; ++pa) {
                if (pa >= npa) break;
#pragma unroll
                for (int i = 0; i < MT; ++i)
#pragma unroll
                    for (int j = 0; j < NT; ++j)
                        acc[i][j] = __builtin_amdgcn_mfma_f32_16x16x32_bf16(
                            af[pa][i], bfr[j], acc[i][j], 0, 0, 0);
            }
        }
    }

#pragma unroll
    for (int i = 0; i < MT; ++i) {
        int mbase = m0 + (aslab0 + i) * 16 + quad * 4;
#pragma unroll
        for (int j = 0; j < NT; ++j) {
            int n = n0 + (bslab0 + j) * 16 + lrow;
            float bv = bias ? bias[n] : 0.f;
#pragma unroll
            for (int r = 0; r < 4; ++r) {
                size_t off = (size_t)(mbase + r) * ldc + n;
                float v = acc[i][j][r] + bv;
                if (act == 1) v = (v > 20.f) ? v : log1pf(__expf(v));
                if (addC) v += C[off];
                C[off] = v;
            }
        }
    }
}

// ---- split-K variant for x_proj: 64x64 tile, K-chunk per blockIdx.z, partials out ----
__global__ __launch_bounds__(256)
void gemm6sk(const float* __restrict__ A, int lda,
             const float* __restrict__ W, int N,
             float* __restrict__ P, int M, int KC)
{
    constexpr int BM = 64, BN = 64, WM = 2, WN = 2;
    constexpr int MT = BM / WM / 16, NT = BN / WN / 16;
    __shared__ short Asl[3][4 * 520];
    __shared__ short Bsl[3][4 * 520];

    const int tid = threadIdx.x;
    const int w = tid >> 6, lane = tid & 63;
    const int lrow = lane & 15, quad = lane >> 4;
    const int aslab0 = (w % WM) * MT;
    const int bslab0 = (w / WM) * NT;
    const int m0 = blockIdx.y * BM, n0 = blockIdx.x * BN;
    const int kbeg = blockIdx.z * KC;

    f32x4 acc[MT][NT] = {};

    for (int k0 = kbeg; k0 < kbeg + KC; k0 += 32) {
        __syncthreads();
#pragma unroll
        for (int i = 0; i < BM / 32; ++i) {
            int v = tid + 256 * i;
            int row = v >> 3;
            int kq = (v & 7) * 4;
            float4 val = *(const float4*)&A[(size_t)(m0 + row) * lda + k0 + kq];
            int off = (row >> 4) * 520 + (((kq >> 3) << 4) + (row & 15)) * 8 + (kq & 7);
            short h[4], mm_[4], l[4];
            split3(val.x, h[0], mm_[0], l[0]);
            split3(val.y, h[1], mm_[1], l[1]);
            split3(val.z, h[2], mm_[2], l[2]);
            split3(val.w, h[3], mm_[3], l[3]);
            *(short4*)&Asl[0][off] = make_short4(h[0], h[1], h[2], h[3]);
            *(short4*)&Asl[1][off] = make_short4(mm_[0], mm_[1], mm_[2], mm_[3]);
            *(short4*)&Asl[2][off] = make_short4(l[0], l[1], l[2], l[3]);
        }
        {
            int v = tid;
            int kp = v >> 4;
            int nc = (v & 15) * 4;
            int k1 = kp * 2;
            float4 r0 = *(const float4*)&W[(size_t)(k0 + k1) * N + n0 + nc];
            float4 r1 = *(const float4*)&W[(size_t)(k0 + k1 + 1) * N + n0 + nc];
            const float e0[4] = {r0.x, r0.y, r0.z, r0.w};
            const float e1[4] = {r1.x, r1.y, r1.z, r1.w};
#pragma unroll
            for (int e = 0; e < 4; ++e) {
                int n = nc + e;
                int off = (n >> 4) * 520 + (((k1 >> 3) << 4) + (n & 15)) * 8 + (k1 & 7);
                short h0, m0_, l0, h1, m1_, l1;
                split3(e0[e], h0, m0_, l0);
                split3(e1[e], h1, m1_, l1);
                *(short2*)&Bsl[0][off] = make_short2(h0, h1);
                *(short2*)&Bsl[1][off] = make_short2(m0_, m1_);
                *(short2*)&Bsl[2][off] = make_short2(l0, l1);
            }
        }
        __syncthreads();

        bf16x8 af[3][MT];
#pragma unroll
        for (int p = 0; p < 3; ++p)
#pragma unroll
            for (int i = 0; i < MT; ++i)
                af[p][i] = *(const bf16x8*)&Asl[p][(aslab0 + i) * 520 + lane * 8];

#pragma unroll
        for (int pb = 0; pb < 3; ++pb) {
            bf16x8 bfr[NT];
#pragma unroll
            for (int j = 0; j < NT; ++j)
                bfr[j] = *(const bf16x8*)&Bsl[pb][(bslab0 + j) * 520 + lane * 8];
            const int npa = (pb == 0) ? 3 : (pb == 1 ? 2 : 1);
#pragma unroll
            for (int pa = 0; pa < 3; ++pa) {
                if (pa >= npa) break;
#pragma unroll
                for (int i = 0; i < MT; ++i)
#pragma unroll
                    for (int j = 0; j < NT; ++j)
                        acc[i][j] = __builtin_amdgcn_mfma_f32_16x16x32_bf16(
                            af[pa][i], bfr[j], acc[i][j], 0, 0, 0);
            }
        }
    }

    float* Pz = P + (size_t)blockIdx.z * M * 64;
#pragma unroll
    for (int i = 0; i < MT; ++i) {
        int mbase = m0 + (aslab0 + i) * 16 + quad * 4;
#pragma unroll
        for (int j = 0; j < NT; ++j) {
            int n = n0 + (bslab0 + j) * 16 + lrow;
#pragma unroll
            for (int r = 0; r < 4; ++r)
                Pz[(size_t)(mbase + r) * 64 + n] = acc[i][j][r];
        }
    }
}

// reduce 8 K-chunk partials -> DBL (float4 over 4096x64)
__global__ __launch_bounds__(256)
void xred_k(const float* __restrict__ P, float* __restrict__ D)
{
    int i = blockIdx.x * 256 + threadIdx.x;
    const float4* p = (const float4*)P;
    float4 a = p[i];
#pragma unroll
    for (int z = 1; z < 8; ++z) {
        float4 b = p[(size_t)z * 65536 + i];
        a.x += b.x; a.y += b.y; a.z += b.z; a.w += b.w;
    }
    ((float4*)D)[i] = a;
}

// ---------------- RMSNorm -> 3 pre-split bf16 planes ----------------
__global__ __launch_bounds__(256)
void rmsnorm3_k(const float* __restrict__ X, const float* __restrict__ w,
                unsigned short* __restrict__ P0, unsigned short* __restrict__ P1,
                unsigned short* __restrict__ P2)
{
    int wid = threadIdx.x >> 6, lane = threadIdx.x & 63;
    int row = blockIdx.x * 4 + wid;
    const float* xr = X + (size_t)row * DMODEL;
    float v[8];
    float ss = 0.f;
#pragma unroll
    for (int j = 0; j < 8; ++j) { v[j] = xr[lane + 64 * j]; ss = fmaf(v[j], v[j], ss); }
#pragma unroll
    for (int off = 32; off >= 1; off >>= 1) ss += __shfl_xor(ss, off);
    float scale = rsqrtf(ss * (1.f / 512.f) + 1e-5f);
#pragma unroll
    for (int j = 0; j < 8; ++j) {
        int col = lane + 64 * j;
        float val = v[j] * scale * w[col];
        short hh, mm, ll;
        split3(val, hh, mm, ll);
        size_t o = (size_t)row * DMODEL + col;
        P0[o] = (unsigned short)hh;
        P1[o] = (unsigned short)mm;
        P2[o] = (unsigned short)ll;
    }
}

// ---------------- causal depthwise conv (K=4) + SiLU, float4 over d ----------------
__global__ __launch_bounds__(256)
void conv_silu_k(const float* __restrict__ XZ, const float* __restrict__ cw,
                 const float* __restrict__ cb, float* __restrict__ XC)
{
    int idx = blockIdx.x * 256 + threadIdx.x;
    int d4 = (idx & 255) * 4;
    int t = (idx >> 8) & 511;
    int b = idx >> 17;
    float4 wv[4];
#pragma unroll
    for (int e = 0; e < 4; ++e) wv[e] = *(const float4*)&cw[(d4 + e) * 4];
    float4 bv = *(const float4*)&cb[d4];
    float s[4] = {bv.x, bv.y, bv.z, bv.w};
#pragma unroll
    for (int k = 0; k < 4; ++k) {
        int tt = t + k - 3;
        if (tt >= 0) {
            float4 x = *(const float4*)&XZ[((size_t)(b * 512 + tt)) * 2048 + d4];
            const float xe[4] = {x.x, x.y, x.z, x.w};
            const float we[4] = {wv[0][k], wv[1][k], wv[2][k], wv[3][k]};
#pragma unroll
            for (int e = 0; e < 4; ++e) s[e] = fmaf(we[e], xe[e], s[e]);
        }
    }
    float4 o;
    o.x = s[0] / (1.f + __expf(-s[0]));
    o.y = s[1] / (1.f + __expf(-s[1]));
    o.z = s[2] / (1.f + __expf(-s[2]));
    o.w = s[3] / (1.f + __expf(-s[3]));
    *(float4*)&XC[((size_t)(b * 512 + t)) * 1024 + d4] = o;
}

// ---------------- chunked selective scan ----------------
// Phase 1: local scan -> local y into XZ xc-half (stride 2048), SC, DS.
__global__ __launch_bounds__(128)
void scan1_k(const float* __restrict__ DELTA, const float* __restrict__ XC,
             const float* __restrict__ DBL, const float* __restrict__ A_log,
             const float* __restrict__ Dsk, float* __restrict__ YL,
             float* __restrict__ SC, float* __restrict__ DS)
{
    __shared__ float BC[64][32];
    const int tid = threadIdx.x;
    const int d = blockIdx.x * 128 + tid;
    const int chunk = blockIdx.y;
    const int b = blockIdx.z;
    const int t0 = chunk * 64;

#pragma unroll
    for (int i = 0; i < 16; ++i) {
        int idx = tid + 128 * i;
        int t = idx >> 5, j = idx & 31;
        BC[t][j] = DBL[(size_t)(b * 512 + t0 + t) * 64 + 32 + j];
    }
    float Ac[16];
#pragma unroll
    for (int n = 0; n < 16; ++n) Ac[n] = -__expf(A_log[d * 16 + n]);
    float Dv = Dsk[d];
    __syncthreads();

    const float* dp = DELTA + ((size_t)(b * 512 + t0)) * 1024 + d;
    const float* up = XC    + ((size_t)(b * 512 + t0)) * 1024 + d;
    float* yp       = YL    + ((size_t)(b * 512 + t0)) * 2048 + d;

    float h[16];
#pragma unroll
    for (int n = 0; n < 16; ++n) h[n] = 0.f;
    float dsum = 0.f;

    for (int tb = 0; tb < 64; tb += 4) {
        float dl[4], ul[4];
#pragma unroll
        for (int j = 0; j < 4; ++j) {
            dl[j] = dp[(tb + j) * 1024];
            ul[j] = up[(tb + j) * 1024];
        }
#pragma unroll
        for (int j = 0; j < 4; ++j) {
            int t = tb + j;
            float delta = dl[j], u = ul[j];
            dsum += delta;
            float du = delta * u;
            float y = 0.f;
#pragma unroll
            for (int n = 0; n < 16; ++n) {
                h[n] = fmaf(__expf(delta * Ac[n]), h[n], du * BC[t][n]);
                y = fmaf(h[n], BC[t][16 + n], y);
            }
            yp[t * 2048] = fmaf(u, Dv, y);
        }
    }

    float* sc = SC + ((size_t)((b * 8 + chunk) * 1024 + d)) * 16;
#pragma unroll
    for (int n = 0; n < 16; ++n) sc[n] = h[n];
    DS[(size_t)(b * 8 + chunk) * 1024 + d] = dsum;
}

__global__ __launch_bounds__(256)
void scan2_k(const float* __restrict__ A_log, float* __restrict__ SC,
             const float* __restrict__ DS)
{
    int gid = blockIdx.x * 256 + threadIdx.x;
    int n = gid & 15;
    int d = (gid >> 4) & 1023;
    int b = gid >> 14;
    float Ac = -__expf(A_log[d * 16 + n]);
    float carry = 0.f;
#pragma unroll
    for (int c = 0; c < 8; ++c) {
        size_t off = ((size_t)((b * 8 + c) * 1024 + d)) * 16 + n;
        float s = SC[off];
        SC[off] = carry;
        carry = fmaf(__expf(Ac * DS[(size_t)(b * 8 + c) * 1024 + d]), carry, s);
    }
}

// Phase 3: y = (ylocal + h0-correction) * silu(z) -> dense fp32 Y (stride 1024)
__global__ __launch_bounds__(128)
void scan3_k(const float* __restrict__ DELTA, const float* __restrict__ DBL,
             const float* __restrict__ A_log, const float* __restrict__ H0,
             const float* __restrict__ XZ, float* __restrict__ Yout)
{
    __shared__ float Cs[64][16];
    const int tid = threadIdx.x;
    const int d = blockIdx.x * 128 + tid;
    const int chunk = blockIdx.y;
    const int b = blockIdx.z;
    const int t0 = chunk * 64;

#pragma unroll
    for (int i = 0; i < 8; ++i) {
        int idx = tid + 128 * i;
        int t = idx >> 4, j = idx & 15;
        Cs[t][j] = DBL[(size_t)(b * 512 + t0 + t) * 64 + 48 + j];
    }
    float Ac[16], h0[16];
#pragma unroll
    for (int n = 0; n < 16; ++n) Ac[n] = -__expf(A_log[d * 16 + n]);
    const float* h0p = H0 + ((size_t)((b * 8 + chunk) * 1024 + d)) * 16;
#pragma unroll
    for (int n = 0; n < 16; ++n) h0[n] = h0p[n];
    __syncthreads();

    const float* dp = DELTA + ((size_t)(b * 512 + t0)) * 1024 + d;
    const float* yl = XZ    + ((size_t)(b * 512 + t0)) * 2048 + d;          // xc half
    const float* zp = XZ    + ((size_t)(b * 512 + t0)) * 2048 + 1024 + d;   // z half
    float* yo       = Yout  + ((size_t)(b * 512 + t0)) * 1024 + d;

    float cum = 0.f;
    for (int tb = 0; tb < 64; tb += 4) {
        float dl[4], yv[4], zl[4];
#pragma unroll
        for (int j = 0; j < 4; ++j) {
            dl[j] = dp[(tb + j) * 1024];
            yv[j] = yl[(tb + j) * 2048];
            zl[j] = zp[(tb + j) * 2048];
        }
#pragma unroll
        for (int j = 0; j < 4; ++j) {
            int t = tb + j;
            float p = 0.f;
            if (chunk != 0) {
                cum += dl[j];
#pragma unroll
                for (int n = 0; n < 16; ++n)
                    p = fmaf(h0[n] * __expf(Ac[n] * cum), Cs[t][n], p);
            }
            float z = zl[j];
            yo[t * 1024] = (yv[j] + p) * (z / (1.f + __expf(-z)));
        }
    }
}

// ---------------- MFMA flash attention, exact fp32 via bf16x6 ----------------
__global__ __launch_bounds__(256, 1)
void attn_mfma(const float* __restrict__ Qm, const float* __restrict__ Km,
               const float* __restrict__ Vm, float* __restrict__ CTX)
{
    __shared__ short KVs[3][16 * 520];
    __shared__ float Ps[4][16 * 260];
    const int tid = threadIdx.x;
    const int w = tid >> 6, lane = tid & 63;
    const int lrow = lane & 15, quad = lane >> 4;
    const int b = blockIdx.z, h = blockIdx.y;
    const int qw = blockIdx.x * 64 + w * 16;

    bf16x8 qf[3][4];
    {
        const float* qp = Qm + ((size_t)(b * 512 + qw + lrow)) * 512 + h * 128 + quad * 8;
#pragma unroll
        for (int kb = 0; kb < 4; ++kb) {
            float4 v0 = *(const float4*)(qp + kb * 32);
            float4 v1 = *(const float4*)(qp + kb * 32 + 4);
            const float e[8] = {v0.x, v0.y, v0.z, v0.w, v1.x, v1.y, v1.z, v1.w};
#pragma unroll
            for (int j = 0; j < 8; ++j) {
                short hh, mm, ll;
                split3(e[j], hh, mm, ll);
                qf[0][kb][j] = hh; qf[1][kb][j] = mm; qf[2][kb][j] = ll;
            }
        }
    }

    const int sdd = (tid & 31) * 4;
    const int skvb = tid >> 5;
    f32x4 sa[4][4] = {};

    float4 kpre[8];
#pragma unroll
    for (int i = 0; i < 8; ++i)
        kpre[i] = *(const float4*)&Km[((size_t)(b * 256 + skvb + 8 * i)) * 512 + h * 128 + sdd];

    for (int c = 0; c < 4; ++c) {
        if (c) __syncthreads();
        {
            const int kb = sdd >> 5, qd = (sdd >> 3) & 3, jd = sdd & 7;
#pragma unroll
            for (int i = 0; i < 8; ++i) {
                int kv = skvb + 8 * i;
                int off = ((kv >> 4) * 4 + kb) * 520 + ((kv & 15) + 16 * qd) * 8 + jd;
                short h0,m0,l0,h1,m1,l1,h2,m2,l2,h3,m3,l3;
                split3(kpre[i].x,h0,m0,l0); split3(kpre[i].y,h1,m1,l1);
                split3(kpre[i].z,h2,m2,l2); split3(kpre[i].w,h3,m3,l3);
                *(short4*)&KVs[0][off] = make_short4(h0,h1,h2,h3);
                *(short4*)&KVs[1][off] = make_short4(m0,m1,m2,m3);
                *(short4*)&KVs[2][off] = make_short4(l0,l1,l2,l3);
            }
        }
        if (c < 3) {
#pragma unroll
            for (int i = 0; i < 8; ++i)
                kpre[i] = *(const float4*)&Km[((size_t)(b * 256 + (c + 1) * 64 + skvb + 8 * i)) * 512 + h * 128 + sdd];
        }
        __syncthreads();
#pragma unroll
        for (int s = 0; s < 4; ++s) {
#pragma unroll
            for (int kb = 0; kb < 4; ++kb) {
                bf16x8 kf[3];
#pragma unroll
                for (int p = 0; p < 3; ++p)
                    kf[p] = *(const bf16x8*)&KVs[p][(s * 4 + kb) * 520 + lane * 8];
                sa[c][s] = __builtin_amdgcn_mfma_f32_16x16x32_bf16(qf[0][kb], kf[0], sa[c][s], 0, 0, 0);
                sa[c][s] = __builtin_amdgcn_mfma_f32_16x16x32_bf16(qf[0][kb], kf[1], sa[c][s], 0, 0, 0);
                sa[c][s] = __builtin_amdgcn_mfma_f32_16x16x32_bf16(qf[1][kb], kf[0], sa[c][s], 0, 0, 0);
                sa[c][s] = __builtin_amdgcn_mfma_f32_16x16x32_bf16(qf[0][kb], kf[2], sa[c][s], 0, 0, 0);
                sa[c][s] = __builtin_amdgcn_mfma_f32_16x16x32_bf16(qf[1][kb], kf[1], sa[c][s], 0, 0, 0);
                sa[c][s] = __builtin_amdgcn_mfma_f32_16x16x32_bf16(qf[2][kb], kf[0], sa[c][s], 0, 0, 0);
            }
        }
    }

    const float scale = 0.08838834764831845f;
    float mx[4] = {-1e30f, -1e30f, -1e30f, -1e30f};
#pragma unroll
    for (int c = 0; c < 4; ++c)
#pragma unroll
        for (int s = 0; s < 4; ++s)
#pragma unroll
            for (int r = 0; r < 4; ++r) {
                sa[c][s][r] *= scale;
                mx[r] = fmaxf(mx[r], sa[c][s][r]);
            }
#pragma unroll
    for (int r = 0; r < 4; ++r) {
        mx[r] = fmaxf(mx[r], __shfl_xor(mx[r], 1));
        mx[r] = fmaxf(mx[r], __shfl_xor(mx[r], 2));
        mx[r] = fmaxf(mx[r], __shfl_xor(mx[r], 4));
        mx[r] = fmaxf(mx[r], __shfl_xor(mx[r], 8));
    }
    float sum[4] = {0.f, 0.f, 0.f, 0.f};
#pragma unroll
    for (int c = 0; c < 4; ++c)
#pragma unroll
        for (int s = 0; s < 4; ++s)
#pragma unroll
            for (int r = 0; r < 4; ++r) {
                float e = __expf(sa[c][s][r] - mx[r]);
                sa[c][s][r] = e;
                sum[r] += e;
            }
#pragma unroll
    for (int r = 0; r < 4; ++r) {
        sum[r] += __shfl_xor(sum[r], 1);
        sum[r] += __shfl_xor(sum[r], 2);
        sum[r] += __shfl_xor(sum[r], 4);
        sum[r] += __shfl_xor(sum[r], 8);
        sum[r] = 1.f / sum[r];
    }
    {
        float* ps = &Ps[w][0];
#pragma unroll
        for (int c = 0; c < 4; ++c)
#pragma unroll
            for (int s = 0; s < 4; ++s)
#pragma unroll
                for (int r = 0; r < 4; ++r)
                    ps[(quad * 4 + r) * 260 + c * 64 + s * 16 + lrow] = sa[c][s][r] * sum[r];
    }

    const int vdd4 = (tid & 31) * 4;
    const int vkvg = tid >> 5;
    f32x4 oa[8] = {};
    float4 vpre[8];
#pragma unroll
    for (int i = 0; i < 2; ++i) {
        int kv0 = (vkvg + 8 * i) * 4;
#pragma unroll
        for (int rr = 0; rr < 4; ++rr)
            vpre[i * 4 + rr] = *(const float4*)&Vm[((size_t)(b * 256 + kv0 + rr)) * 512 + h * 128 + vdd4];
    }

    for (int c = 0; c < 4; ++c) {
        __syncthreads();
        {
#pragma unroll
            for (int i = 0; i < 2; ++i) {
                int kv0 = (vkvg + 8 * i) * 4;
                int kb2 = kv0 >> 5, qk = (kv0 >> 3) & 3, jb = kv0 & 7;
                const float4 r0 = vpre[i * 4 + 0], r1 = vpre[i * 4 + 1];
                const float4 r2 = vpre[i * 4 + 2], r3 = vpre[i * 4 + 3];
                const float ve[4][4] = {{r0.x, r1.x, r2.x, r3.x},
                                        {r0.y, r1.y, r2.y, r3.y},
                                        {r0.z, r1.z, r2.z, r3.z},
                                        {r0.w, r1.w, r2.w, r3.w}};
#pragma unroll
                for (int e = 0; e < 4; ++e) {
                    int dd = vdd4 + e;
                    int off = ((dd >> 4) * 2 + kb2) * 520 + ((dd & 15) + 16 * qk) * 8 + jb;
                    short h0,m0,l0,h1,m1,l1,h2,m2,l2,h3,m3,l3;
                    split3(ve[e][0],h0,m0,l0); split3(ve[e][1],h1,m1,l1);
                    split3(ve[e][2],h2,m2,l2); split3(ve[e][3],h3,m3,l3);
                    *(short4*)&KVs[0][off] = make_short4(h0,h1,h2,h3);
                    *(short4*)&KVs[1][off] = make_short4(m0,m1,m2,m3);
                    *(short4*)&KVs[2][off] = make_short4(l0,l1,l2,l3);
                }
            }
        }
        if (c < 3) {
#pragma unroll
            for (int i = 0; i < 2; ++i) {
                int kv0 = (vkvg + 8 * i) * 4;
#pragma unroll
                for (int rr = 0; rr < 4; ++rr)
                    vpre[i * 4 + rr] = *(const float4*)&Vm[((size_t)(b * 256 + (c + 1) * 64 + kv0 + rr)) * 512 + h * 128 + vdd4];
            }
        }
        __syncthreads();
#pragma unroll
        for (int kb2 = 0; kb2 < 2; ++kb2) {
            const float* pp = &Ps[w][lrow * 260 + c * 64 + kb2 * 32 + quad * 8];
            float4 a0 = *(const float4*)pp;
            float4 a1 = *(const float4*)(pp + 4);
            const float e[8] = {a0.x, a0.y, a0.z, a0.w, a1.x, a1.y, a1.z, a1.w};
            bf16x8 af[3];
#pragma unroll
            for (int j = 0; j < 8; ++j) {
                short hh, mm, ll;
                split3(e[j], hh, mm, ll);
                af[0][j] = hh; af[1][j] = mm; af[2][j] = ll;
            }
#pragma unroll
            for (int s = 0; s < 8; ++s) {
                bf16x8 vf[3];
#pragma unroll
                for (int p = 0; p < 3; ++p)
                    vf[p] = *(const bf16x8*)&KVs[p][(s * 2 + kb2) * 520 + lane * 8];
                oa[s] = __builtin_amdgcn_mfma_f32_16x16x32_bf16(af[0], vf[0], oa[s], 0, 0, 0);
                oa[s] = __builtin_amdgcn_mfma_f32_16x16x32_bf16(af[0], vf[1], oa[s], 0, 0, 0);
                oa[s] = __builtin_amdgcn_mfma_f32_16x16x32_bf16(af[1], vf[0], oa[s], 0, 0, 0);
                oa[s] = __builtin_amdgcn_mfma_f32_16x16x32_bf16(af[0], vf[2], oa[s], 0, 0, 0);
                oa[s] = __builtin_amdgcn_mfma_f32_16x16x32_bf16(af[1], vf[1], oa[s], 0, 0, 0);
                oa[s] = __builtin_amdgcn_mfma_f32_16x16x32_bf16(af[2], vf[0], oa[s], 0, 0, 0);
            }
        }
    }

#pragma unroll
    for (int s = 0; s < 8; ++s)
#pragma unroll
        for (int r = 0; r < 4; ++r)
            CTX[((size_t)(b * 512 + qw + quad * 4 + r)) * 512 + h * 128 + s * 16 + lrow] = oa[s][r];
}

// ---------------- final linear (512->6) + argmax, one wave per row ----------------
__global__ __launch_bounds__(256)
void head_k(const float* __restrict__ T2, const float* __restrict__ Wout,
            const float* __restrict__ bout, float* __restrict__ out)
{
    int wid = threadIdx.x >> 6, lane = threadIdx.x & 63;
    int row = blockIdx.x * 4 + wid;
    float acc[6] = {0.f, 0.f, 0.f, 0.f, 0.f, 0.f};
    const float* tr = T2 + (size_t)row * 512;
#pragma unroll
    for (int j = 0; j < 8; ++j) {
        int k = lane + 64 * j;
        float t = tr[k];
#pragma unroll
        for (int c = 0; c < 6; ++c) acc[c] = fmaf(t, Wout[k * 6 + c], acc[c]);
    }
#pragma unroll
    for (int c = 0; c < 6; ++c) {
#pragma unroll
        for (int off = 32; off >= 1; off >>= 1) acc[c] += __shfl_xor(acc[c], off);
    }
    if (lane == 0) {
        float best = -1e30f;
        int bi = 0;
#pragma unroll
        for (int c = 0; c < 6; ++c) {
            float v = acc[c] + bout[c];
            out[(size_t)row * 6 + c] = v;
            if (v > best) { best = v; bi = c; }
        }
        out[(size_t)4096 * 6 + row] = (float)bi;
    }
}

extern "C" void kernel_launch(void* const* d_in, const int* in_sizes, int n_in,
                              void* d_out, int out_size, void* d_ws, size_t ws_size,
                              hipStream_t stream)
{
    (void)in_sizes; (void)n_in; (void)out_size; (void)ws_size;
    const float* agent      = (const float*)d_in[0];
    const float* lane       = (const float*)d_in[1];
    const float* lane_in_W  = (const float*)d_in[2];
    const float* lane_in_b  = (const float*)d_in[3];
    const float* norm_w     = (const float*)d_in[4];
    const float* in_proj_W  = (const float*)d_in[5];
    const float* conv_w     = (const float*)d_in[6];
    const float* conv_b     = (const float*)d_in[7];
    const float* x_proj_W   = (const float*)d_in[8];
    const float* dt_proj_W  = (const float*)d_in[9];
    const float* dt_proj_b  = (const float*)d_in[10];
    const float* A_log      = (const float*)d_in[11];
    const float* D_skip     = (const float*)d_in[12];
    const float* out_proj_W = (const float*)d_in[13];
    const float* final_norm_w = (const float*)d_in[14];
    const float* Wq = (const float*)d_in[15];
    const float* Wk = (const float*)d_in[16];
    const float* Wv = (const float*)d_in[17];
    const float* Wo = (const float*)d_in[18];
    const float* bq = (const float*)d_in[19];
    const float* bk = (const float*)d_in[20];
    const float* bv = (const float*)d_in[21];
    const float* bo = (const float*)d_in[22];
    const float* lin_in_W  = (const float*)d_in[23];
    const float* lin_in_b  = (const float*)d_in[24];
    const float* lin_out_W = (const float*)d_in[25];
    const float* lin_out_b = (const float*)d_in[26];

    // Workspace: same 97 MB footprint (rounds 1/3-11). Lifetime-audited aliases:
    //  - local y in XZ xc-half (dead after conv), gated fp32 Y in Y (dense)
    //  - Hp2 in Y[0:4MB] (dead after in_proj/Wq), PART in Y[4:12MB] (dead after xred)
    //  - out_proj/in_proj W planes at XC (dead windows), dt W planes at H+6MB
    float* ws = (float*)d_ws;
    float* X     = ws;                      // 2M floats (4096 x 512)
    float* H     = X + (1 << 21);           // 2M
    float* XZ    = H + (1 << 21);           // 8M  (4096 x 2048)
    float* XC    = XZ + (1 << 23);          // 4M  (4096 x 1024)
    float* DELTA = XC + (1 << 22);          // 4M
    float* Y     = DELTA + (1 << 22);       // 4M
    float* DBL   = Y + (1 << 22);           // 256K (4096 x 64)
    unsigned short* Hp0 = (unsigned short*)H;
    unsigned short* Hp1 = (unsigned short*)(H + (1 << 20));
    unsigned short* Hp2 = (unsigned short*)Y;
    float* PART  = Y + (1 << 20);           // x_proj split-K partials (8MB)
    float* SCb   = H;
    float* DSb   = H + (1 << 20);
    short* DTWP  = (short*)(H + 3 * (1 << 19));   // dt W planes, post-in_proj window
    short* WPL   = (short*)XC;              // JIT weight planes
    float* Qb  = XZ;                        // MHA phase
    float* Kb  = XZ + (1 << 21);
    float* Vb  = Kb + (1 << 20);
    float* CTX = Vb + (1 << 20);
    float* AO  = CTX + (1 << 21);
    float* T2  = DELTA;

    dim3 blk(256);
    dim3 sblk(128);
    dim3 sgrid(8, 8, 8);

    // x = lane_features @ lane_in_W + b
    wsplit_k<<<32, blk, 0, stream>>>(lane_in_W, WPL, 128, 512);
    gemm6g<128, 64, 2, 2><<<dim3(8, 32), blk, 0, stream>>>(
        lane, 128, WPL, lane_in_b, X, 512, 4096, 512, 128, 0, 0);

    for (int i = 0; i < 4; ++i) {
        rmsnorm3_k<<<1024, blk, 0, stream>>>(X, norm_w + i * 512, Hp0, Hp1, Hp2);
        wsplit_k<<<512, blk, 0, stream>>>(in_proj_W + (size_t)i * 512 * 2048, WPL, 512, 2048);
        gemm6f<128, 128, 2, 2><<<dim3(16, 32), blk, 0, stream>>>(
            Hp0, Hp1, Hp2, 512, WPL, nullptr, XZ, 2048, 4096, 2048, 512, 0, 0);
        conv_silu_k<<<4096, blk, 0, stream>>>(XZ, conv_w + i * 4096, conv_b + i * 1024, XC);
        gemm6sk<<<dim3(1, 64, 8), blk, 0, stream>>>(
            XC, 1024, x_proj_W + (size_t)i * 1024 * 64, 64, PART, 4096, 128);
        xred_k<<<256, blk, 0, stream>>>(PART, DBL);
        // dt_proj with pre-split W
        wsplit_k<<<16, blk, 0, stream>>>(dt_proj_W + (size_t)i * 32 * 1024, DTWP, 32, 1024);
        gemm6g<128, 64, 2, 2><<<dim3(16, 32), blk, 0, stream>>>(
            DBL, 64, DTWP, dt_proj_b + i * 1024, DELTA, 1024, 4096, 1024, 32, 1, 0);
        // scans: local y -> XZ xc-half; phase 3 gates -> dense fp32 Y
        scan1_k<<<sgrid, sblk, 0, stream>>>(DELTA, XC, DBL, A_log + (size_t)i * 1024 * 16,
                                            D_skip + i * 1024, XZ, SCb, DSb);
        scan2_k<<<512, blk, 0, stream>>>(A_log + (size_t)i * 1024 * 16, SCb, DSb);
        wsplit_k<<<256, blk, 0, stream>>>(out_proj_W + (size_t)i * 1024 * 512, WPL, 1024, 512);
        scan3_k<<<sgrid, sblk, 0, stream>>>(DELTA, DBL, A_log + (size_t)i * 1024 * 16,
                                            SCb, XZ, Y);
        // x += ygated @ out_proj: fp32 A (dense Y), pre-split W
        gemm6g<64, 64, 2, 2><<<dim3(8, 64), blk, 0, stream>>>(
            Y, 1024, WPL, nullptr, X, 512, 4096, 512, 1024, 0, 1);
    }

    rmsnorm3_k<<<1024, blk, 0, stream>>>(X, final_norm_w, Hp0, Hp1, Hp2);

    // fused MHA weight presplits into XC
    short* WPq = WPL;
    short* WPk = WPL + 786432;
    short* WPv = WPL + 2 * 786432;
    short* WPo = WPL + 3 * 786432;
    short* WPn = WPL + 4 * 786432;
    wsplit5_k<<<dim3(128, 5), blk, 0, stream>>>(Wq, Wk, Wv, Wo, lin_in_W, WPL);

    gemm6f<128, 64, 2, 2><<<dim3(8, 32), blk, 0, stream>>>(
        Hp0, Hp1, Hp2, 512, WPq, bq, Qb, 512, 4096, 512, 512, 0, 0);
    gemm6g<64, 64, 2, 2><<<dim3(8, 32), blk, 0, stream>>>(
        agent, 512, WPk, bk, Kb, 512, 2048, 512, 512, 0, 0);
    gemm6g<64, 64, 2, 2><<<dim3(8, 32), blk, 0, stream>>>(
        agent, 512, WPv, bv, Vb, 512, 2048, 512, 512, 0, 0);
    attn_mfma<<<dim3(8, 4, 8), blk, 0, stream>>>(Qb, Kb, Vb, CTX);
    gemm6g<64, 64, 2, 2><<<dim3(8, 64), blk, 0, stream>>>(
        CTX, 512, WPo, bo, AO, 512, 4096, 512, 512, 0, 0);
    gemm6g<64, 64, 2, 2><<<dim3(8, 64), blk, 0, stream>>>(
        AO, 512, WPn, lin_in_b, T2, 512, 4096, 512, 512, 0, 0);
    head_k<<<1024, blk, 0, stream>>>(T2, lin_out_W, lin_out_b, (float*)d_out);
}